// Round 4
// baseline (118.993 us; speedup 1.0000x reference)
//
#include <hip/hip_runtime.h>
#include <stdint.h>

#define D 2048
#define R 64
#define M_TOTAL 8192

typedef float f32x4 __attribute__((ext_vector_type(4)));
typedef __bf16 bf16x8 __attribute__((ext_vector_type(8)));
typedef unsigned short u16x8 __attribute__((ext_vector_type(8)));
typedef unsigned short u16x4 __attribute__((ext_vector_type(4)));

__device__ __forceinline__ unsigned short f2bf(float f) {
  unsigned u = __builtin_bit_cast(unsigned, f);
  u += 0x7FFFu + ((u >> 16) & 1u);
  return (unsigned short)(u >> 16);
}

__device__ __forceinline__ void gload_lds16(const void* g, void* l) {
  __builtin_amdgcn_global_load_lds(
      (const __attribute__((address_space(1))) void*)g,
      (__attribute__((address_space(3))) void*)l, 16, 0, 0);
}

// ---------------- fused prep ----------------
// blocks 0..127   : x f32->bf16 (writes xbf) fused with h = bf16(gelu(x@W1^T+b1))
// blocks 128..1151: St[n][k] = bf16(A[k][n]+B[k][n]+C[k][n])
// blocks 1152..1159: W2 f32->bf16
__global__ __launch_bounds__(256) void prep_kernel(
    const float* __restrict__ x, const float* __restrict__ A,
    const float* __restrict__ B, const float* __restrict__ C,
    const float* __restrict__ w1, const float* __restrict__ b1,
    const float* __restrict__ w2,
    unsigned short* __restrict__ xbf, unsigned short* __restrict__ st,
    unsigned short* __restrict__ w2bf, unsigned short* __restrict__ hbf) {
  __shared__ unsigned short plds[10240];  // 20 KB, shared by roles
  int t = threadIdx.x;
  int bx = blockIdx.x;
  if (bx < 128) {
    // ---- fused x-conv + h ----
    int m0 = bx * 64;
    int row = t >> 2, c8 = (t & 3) * 8;
    const float* xp = x + (size_t)(m0 + row) * D + c8;
    const float* wp = w1 + (size_t)row * D + c8;  // row in [0,64) == R rows
    unsigned short* xop = xbf + (size_t)(m0 + row) * D + c8;
    unsigned short* sX = plds;          // [2][64*40] padded stride 40
    unsigned short* sW = plds + 5120;
    int w = t >> 6, lm = t & 15, lk = (t & 63) >> 4;
    f32x4 acc[4] = {};
    float4 rx0 = *(const float4*)(xp);
    float4 rx1 = *(const float4*)(xp + 4);
    float4 rw0 = *(const float4*)(wp);
    float4 rw1 = *(const float4*)(wp + 4);
#pragma unroll 1
    for (int kt = 0; kt < 64; ++kt) {
      int buf = (kt & 1) * 2560;
      u16x8 ox = { f2bf(rx0.x), f2bf(rx0.y), f2bf(rx0.z), f2bf(rx0.w),
                   f2bf(rx1.x), f2bf(rx1.y), f2bf(rx1.z), f2bf(rx1.w) };
      u16x8 ow = { f2bf(rw0.x), f2bf(rw0.y), f2bf(rw0.z), f2bf(rw0.w),
                   f2bf(rw1.x), f2bf(rw1.y), f2bf(rw1.z), f2bf(rw1.w) };
      *(u16x8*)(sX + buf + row * 40 + c8) = ox;
      *(u16x8*)(sW + buf + row * 40 + c8) = ow;
      *(u16x8*)(xop + kt * 32) = ox;
      __syncthreads();
      if (kt < 63) {
        rx0 = *(const float4*)(xp + (kt + 1) * 32);
        rx1 = *(const float4*)(xp + (kt + 1) * 32 + 4);
        rw0 = *(const float4*)(wp + (kt + 1) * 32);
        rw1 = *(const float4*)(wp + (kt + 1) * 32 + 4);
      }
      bf16x8 a = __builtin_bit_cast(bf16x8, *(const u16x8*)(sX + buf + (w * 16 + lm) * 40 + lk * 8));
#pragma unroll
      for (int j = 0; j < 4; ++j) {
        bf16x8 b = __builtin_bit_cast(bf16x8, *(const u16x8*)(sW + buf + (j * 16 + lm) * 40 + lk * 8));
        acc[j] = __builtin_amdgcn_mfma_f32_16x16x32_bf16(a, b, acc[j], 0, 0, 0);
      }
    }
    int m_base = m0 + w * 16 + lk * 4;
#pragma unroll
    for (int j = 0; j < 4; ++j) {
      int n = j * 16 + lm;
      float bv = b1[n];
#pragma unroll
      for (int r = 0; r < 4; ++r) {
        float v = acc[j][r] + bv;
        float g = 0.5f * v * (1.0f + erff(v * 0.70710678118654752f));
        hbf[(size_t)(m_base + r) * R + n] = f2bf(g);
      }
    }
  } else if (bx < 1152) {
    // ---- sumt ----
    unsigned short (*lds)[68] = (unsigned short(*)[68])plds;
    int id = bx - 128;
    int tk = id >> 5, tn = id & 31;
    int k0 = tk * 64, n0 = tn * 64;
#pragma unroll
    for (int q = 0; q < 4; ++q) {
      int row = q * 16 + (t >> 4);
      int col = (t & 15) * 4;
      size_t off = (size_t)(k0 + row) * D + n0 + col;
      float4 a = *(const float4*)(A + off);
      float4 b = *(const float4*)(B + off);
      float4 c = *(const float4*)(C + off);
      u16x4 o = { f2bf(a.x + b.x + c.x), f2bf(a.y + b.y + c.y),
                  f2bf(a.z + b.z + c.z), f2bf(a.w + b.w + c.w) };
      *(u16x4*)(&lds[row][col]) = o;
    }
    __syncthreads();
    int n = t >> 2, kc = (t & 3) * 16;
    u16x8 v0, v1;
#pragma unroll
    for (int jj = 0; jj < 8; ++jj) v0[jj] = lds[kc + jj][n];
#pragma unroll
    for (int jj = 0; jj < 8; ++jj) v1[jj] = lds[kc + 8 + jj][n];
    size_t ooff = (size_t)(n0 + n) * D + k0 + kc;
    *(u16x8*)(st + ooff) = v0;
    *(u16x8*)(st + ooff + 8) = v1;
  } else {
    // ---- W2 conv ----
    const int NW4 = (D * R) / 4;  // 32768
    for (int i = (bx - 1152) * 256 + t; i < NW4; i += 8 * 256) {
      float4 v = ((const float4*)w2)[i];
      u16x4 o = { f2bf(v.x), f2bf(v.y), f2bf(v.z), f2bf(v.w) };
      *(u16x4*)(w2bf + (size_t)i * 4) = o;
    }
  }
}

// ---------------- main: out = (x @ S) * dt + Dp ----------------
// 256x256 tile, BK=64, 8 waves (2M x 4N), 4-phase schedule. All 4 half-tiles
// of tile kt+1 staged EARLY in tile kt (A0,A1 @P0; B0 @P1; B1 @P2) so the
// single end-of-tile drain has >=1.5 phases of issue-to-wait distance.
__global__ __launch_bounds__(512, 2) void gemm_kernel(
    const unsigned short* __restrict__ xbf, const unsigned short* __restrict__ st,
    const unsigned short* __restrict__ hbf, const unsigned short* __restrict__ w2bf,
    const float* __restrict__ b2, const float* __restrict__ dp,
    float* __restrict__ out) {
  __shared__ unsigned short sA[2 * 16384];  // 2 bufs x 256 rows x 64 k, 64 KB
  __shared__ unsigned short sB[2 * 16384];  // 64 KB
  const int tid = threadIdx.x;
  const int w = tid >> 6, l = tid & 63, lk = l >> 4, lm = l & 15;
  const int wm = w >> 2, wn = w & 3;
  int bid = blockIdx.x;
  int wg = (bid & 7) * 32 + (bid >> 3);  // bijective XCD swizzle (256 wgs)
  int mb = wg >> 3, nb = wg & 7;
  int m0 = mb * 256, n0 = nb * 256;

  // staging: chunk p = q*512 + tid; row = p>>3; phys granule gp = p&7;
  // logical granule kg = gp ^ (row&7) -- same value for q=0/1 (row +64).
  const int kg = (tid & 7) ^ ((tid >> 3) & 7);
  const unsigned short* gA = xbf + (size_t)(m0 + (tid >> 3)) * D + kg * 8;
  const unsigned short* gB = st + (size_t)(n0 + (tid >> 3)) * D + kg * 8;
  const int dstw = w * 512;  // shorts; wave-uniform base (HW adds lane*16B)

  // fragment reads: phys granule = (kk*4+lk) ^ (lm&7)
  const int s7 = lm & 7;
  const int gsw0 = (lk ^ s7) * 8;        // kk=0
  const int gsw1 = ((4 | lk) ^ s7) * 8;  // kk=1
  const int arow = (wm * 128 + lm) * 64;
  const int brow = (wn * 64 + lm) * 64;

  f32x4 acc[8][4] = {};

#define STAGE(gptr, sbuf, T, h) do { \
    const unsigned short* g_ = (gptr) + (size_t)((h) * 128) * D + (T) * 64; \
    unsigned short* d_ = (sbuf) + (((T) & 1) * 16384 + (h) * 8192 + dstw); \
    gload_lds16(g_, d_); \
    gload_lds16(g_ + 64 * D, d_ + 4096); } while (0)

#define LD8(buf, off) __builtin_bit_cast(bf16x8, *(const u16x8*)((buf) + (off)))

  // prologue: tile0 all 4 halves; drain
  STAGE(gA, sA, 0, 0); STAGE(gA, sA, 0, 1);
  STAGE(gB, sB, 0, 0); STAGE(gB, sB, 0, 1);
  asm volatile("s_waitcnt vmcnt(0)" ::: "memory");
  __builtin_amdgcn_s_barrier();

  const int NT = D / 64;  // 32
#pragma unroll 1
  for (int kt = 0; kt < NT; ++kt) {
    const unsigned short* bufA = sA + (kt & 1) * 16384;
    const unsigned short* bufB = sB + (kt & 1) * 16384;
    bf16x8 a[4][2], b0[2][2], b1[2][2];

    // ---- P0: read A03 + B01 frags; stage kt+1.A0, kt+1.A1
    #pragma unroll
    for (int i = 0; i < 4; ++i) {
      a[i][0] = LD8(bufA, arow + i * 1024 + gsw0);
      a[i][1] = LD8(bufA, arow + i * 1024 + gsw1);
    }
    #pragma unroll
    for (int j = 0; j < 2; ++j) {
      b0[j][0] = LD8(bufB, brow + j * 1024 + gsw0);
      b0[j][1] = LD8(bufB, brow + j * 1024 + gsw1);
    }
    if (kt + 1 < NT) { STAGE(gA, sA, kt + 1, 0); STAGE(gA, sA, kt + 1, 1); }
    __builtin_amdgcn_s_barrier();
    asm volatile("s_waitcnt lgkmcnt(0)" ::: "memory");
    __builtin_amdgcn_s_setprio(1);
    #pragma unroll
    for (int i = 0; i < 4; ++i)
      #pragma unroll
      for (int j = 0; j < 2; ++j) {
        acc[i][j] = __builtin_amdgcn_mfma_f32_16x16x32_bf16(a[i][0], b0[j][0], acc[i][j], 0, 0, 0);
        acc[i][j] = __builtin_amdgcn_mfma_f32_16x16x32_bf16(a[i][1], b0[j][1], acc[i][j], 0, 0, 0);
      }
    __builtin_amdgcn_s_setprio(0);
    __builtin_amdgcn_s_barrier();

    // ---- P1: read B23; stage kt+1.B0; MFMA Q(0,1)
    #pragma unroll
    for (int j = 0; j < 2; ++j) {
      b1[j][0] = LD8(bufB, brow + (j + 2) * 1024 + gsw0);
      b1[j][1] = LD8(bufB, brow + (j + 2) * 1024 + gsw1);
    }
    if (kt + 1 < NT) STAGE(gB, sB, kt + 1, 0);
    __builtin_amdgcn_s_barrier();
    asm volatile("s_waitcnt lgkmcnt(0)" ::: "memory");
    __builtin_amdgcn_s_setprio(1);
    #pragma unroll
    for (int i = 0; i < 4; ++i)
      #pragma unroll
      for (int j = 0; j < 2; ++j) {
        acc[i][j + 2] = __builtin_amdgcn_mfma_f32_16x16x32_bf16(a[i][0], b1[j][0], acc[i][j + 2], 0, 0, 0);
        acc[i][j + 2] = __builtin_amdgcn_mfma_f32_16x16x32_bf16(a[i][1], b1[j][1], acc[i][j + 2], 0, 0, 0);
      }
    __builtin_amdgcn_s_setprio(0);
    __builtin_amdgcn_s_barrier();

    // ---- P2: read A47 (reuse regs); stage kt+1.B1; MFMA Q(1,1)
    #pragma unroll
    for (int i = 0; i < 4; ++i) {
      a[i][0] = LD8(bufA, arow + (i + 4) * 1024 + gsw0);
      a[i][1] = LD8(bufA, arow + (i + 4) * 1024 + gsw1);
    }
    if (kt + 1 < NT) STAGE(gB, sB, kt + 1, 1);
    __builtin_amdgcn_s_barrier();
    asm volatile("s_waitcnt lgkmcnt(0)" ::: "memory");
    __builtin_amdgcn_s_setprio(1);
    #pragma unroll
    for (int i = 0; i < 4; ++i)
      #pragma unroll
      for (int j = 0; j < 2; ++j) {
        acc[i + 4][j + 2] = __builtin_amdgcn_mfma_f32_16x16x32_bf16(a[i][0], b1[j][0], acc[i + 4][j + 2], 0, 0, 0);
        acc[i + 4][j + 2] = __builtin_amdgcn_mfma_f32_16x16x32_bf16(a[i][1], b1[j][1], acc[i + 4][j + 2], 0, 0, 0);
      }
    __builtin_amdgcn_s_setprio(0);
    __builtin_amdgcn_s_barrier();

    // ---- P3: no reads/stages; MFMA Q(1,0); drain tile kt+1 (distance >=1.5 phases)
    __builtin_amdgcn_s_setprio(1);
    #pragma unroll
    for (int i = 0; i < 4; ++i)
      #pragma unroll
      for (int j = 0; j < 2; ++j) {
        acc[i + 4][j] = __builtin_amdgcn_mfma_f32_16x16x32_bf16(a[i][0], b0[j][0], acc[i + 4][j], 0, 0, 0);
        acc[i + 4][j] = __builtin_amdgcn_mfma_f32_16x16x32_bf16(a[i][1], b0[j][1], acc[i + 4][j], 0, 0, 0);
      }
    __builtin_amdgcn_s_setprio(0);
    asm volatile("s_waitcnt vmcnt(0)" ::: "memory");
    __builtin_amdgcn_s_barrier();
  }

  // epilogue: dt = h @ W2^T + b2 (rank-64), out = acc*dt + Dp
  bf16x8 wb0[4], wb1[4];
  float b2v[4], dpv[4];
#pragma unroll
  for (int j = 0; j < 4; ++j) {
    int n = n0 + wn * 64 + j * 16 + lm;
    const u16x8* wp = (const u16x8*)(w2bf + (size_t)n * R + lk * 8);
    wb0[j] = __builtin_bit_cast(bf16x8, wp[0]);
    wb1[j] = __builtin_bit_cast(bf16x8, wp[4]);  // +32 bf16
    b2v[j] = b2[n];
    dpv[j] = dp[n];
  }
#pragma unroll
  for (int mi = 0; mi < 8; ++mi) {
    int hrow = m0 + wm * 128 + mi * 16 + lm;
    const u16x8* hp = (const u16x8*)(hbf + (size_t)hrow * R + lk * 8);
    bf16x8 ha0 = __builtin_bit_cast(bf16x8, hp[0]);
    bf16x8 ha1 = __builtin_bit_cast(bf16x8, hp[4]);
    int mbase = m0 + wm * 128 + mi * 16 + lk * 4;
#pragma unroll
    for (int j = 0; j < 4; ++j) {
      f32x4 dt = {};
      dt = __builtin_amdgcn_mfma_f32_16x16x32_bf16(ha0, wb0[j], dt, 0, 0, 0);
      dt = __builtin_amdgcn_mfma_f32_16x16x32_bf16(ha1, wb1[j], dt, 0, 0, 0);
      int n = n0 + wn * 64 + j * 16 + lm;
#pragma unroll
      for (int r = 0; r < 4; ++r) {
        float val = acc[mi][j][r] * (dt[r] + b2v[j]) + dpv[j];
        out[(size_t)(mbase + r) * D + n] = val;
      }
    }
  }
#undef STAGE
#undef LD8
}

extern "C" void kernel_launch(void* const* d_in, const int* in_sizes, int n_in,
                              void* d_out, int out_size, void* d_ws, size_t ws_size,
                              hipStream_t stream) {
  const float* x  = (const float*)d_in[0];
  const float* A  = (const float*)d_in[1];
  const float* B  = (const float*)d_in[2];
  const float* C  = (const float*)d_in[3];
  const float* Dp = (const float*)d_in[4];
  const float* W1 = (const float*)d_in[5];
  const float* b1 = (const float*)d_in[6];
  const float* W2 = (const float*)d_in[7];
  const float* b2 = (const float*)d_in[8];
  float* out = (float*)d_out;

  uint8_t* ws = (uint8_t*)d_ws;
  unsigned short* xbf  = (unsigned short*)ws;                                // 32 MB
  unsigned short* st   = (unsigned short*)(ws + (32u << 20));                // 8 MB
  unsigned short* w2bf = (unsigned short*)(ws + (40u << 20));                // 256 KB
  unsigned short* hbf  = (unsigned short*)(ws + (41u << 20));                // 1 MB

  prep_kernel<<<1160, 256, 0, stream>>>(x, A, B, C, W1, b1, W2, xbf, st, w2bf, hbf);
  gemm_kernel<<<256, 512, 0, stream>>>(xbf, st, hbf, w2bf, b2, Dp, out);
}